// Round 1
// baseline (3463.055 us; speedup 1.0000x reference)
//
#include <hip/hip_runtime.h>
#include <math.h>

#define EPS_BN 1e-5f

// Problem constants (from reference setup_inputs):
// B=32, NS=200, NQ=100, C=8, L=512, H=32, F=128, N_WAY=20
#define NSUP   6400      // B*NS
#define NQRY   3200      // B*NQ
#define NSAMP  9600
#define NWAY   20
#define NSHOTB 200       // NS per batch
#define NQB    100       // NQ per batch

// ---------------------------------------------------------------------------
// Encoder: one block per sample. 256 threads.
// LDS region aliasing (all offsets in floats):
//   region A (0..8319):      I  = input  8 x 514 (halo at col 0 and 513)
//                            B2 = conv2 out 64 x 130 (halo cols) [after I dead]
//   region B (8320..16575):  B1 = conv1 out 32 x 258 (halo cols)
//                            B3 = conv3 out 128 x 64           [after B1 dead]
// ---------------------------------------------------------------------------
__global__ __launch_bounds__(256) void encoder_kernel(
    const float* __restrict__ s_img, const float* __restrict__ q_img,
    const float* __restrict__ pw1, const float* __restrict__ pb1,
    const float* __restrict__ pg1, const float* __restrict__ pbe1,
    const float* __restrict__ pm1, const float* __restrict__ pv1,
    const float* __restrict__ pw2, const float* __restrict__ pb2,
    const float* __restrict__ pg2, const float* __restrict__ pbe2,
    const float* __restrict__ pm2, const float* __restrict__ pv2,
    const float* __restrict__ pw3, const float* __restrict__ pb3,
    const float* __restrict__ pg3, const float* __restrict__ pbe3,
    const float* __restrict__ pm3, const float* __restrict__ pv3,
    const float* __restrict__ pwf, const float* __restrict__ pbf,
    const float* __restrict__ pgf, const float* __restrict__ pbef,
    const float* __restrict__ pmf, const float* __restrict__ pvf,
    float* __restrict__ feat_out)
{
    __shared__ float smem[16576];
    __shared__ float sc1[32], sh1[32], sc2[64], sh2[64], sc3[128], sh3[128];
    __shared__ float featm[128], featr[128];

    float* const I  = smem;           // 8 x 514   = 4112 floats
    float* const B2 = smem;           // 64 x 130  = 8320 floats (aliases I)
    float* const B1 = smem + 8320;    // 32 x 258  = 8256 floats
    float* const B3 = smem + 8320;    // 128 x 64  = 8192 floats (aliases B1)

    const int tid = threadIdx.x;
    const int sid = blockIdx.x;
    const float* xin = (sid < NSUP) ? (s_img + (size_t)sid * 4096)
                                    : (q_img + (size_t)(sid - NSUP) * 4096);

    // ---- stage 0: fold BN params (scale/shift), load input, zero halos ----
    if (tid < 32) {
        float s = pg1[tid] * rsqrtf(pv1[tid] + EPS_BN);
        sc1[tid] = s; sh1[tid] = (pb1[tid] - pm1[tid]) * s + pbe1[tid];
    } else if (tid < 96) {
        int c = tid - 32;
        float s = pg2[c] * rsqrtf(pv2[c] + EPS_BN);
        sc2[c] = s; sh2[c] = (pb2[c] - pm2[c]) * s + pbe2[c];
    } else if (tid < 224) {
        int c = tid - 96;
        float s = pg3[c] * rsqrtf(pv3[c] + EPS_BN);
        sc3[c] = s; sh3[c] = (pb3[c] - pm3[c]) * s + pbe3[c];
    }
    if (tid < 32) { B1[tid*258] = 0.f; B1[tid*258 + 257] = 0.f; }
    #pragma unroll
    for (int k = 0; k < 4; ++k) {
        int p = k*256 + tid;                 // float4 index, 1024 total
        float4 v = ((const float4*)xin)[p];
        int fi = p * 4;
        int ci = fi >> 9;
        int l  = fi & 511;
        float* dst = &I[ci*514 + 1 + l];
        dst[0] = v.x; dst[1] = v.y; dst[2] = v.z; dst[3] = v.w;
    }
    if (tid < 8) { I[tid*514] = 0.f; I[tid*514 + 513] = 0.f; }
    __syncthreads();

    // ---- stage 1: conv1 (8 -> 32, L=512) + BN + ReLU + pool2 -> B1 ----
    {
        const int lp = tid;  // 0..255 pooled position
        float a0[32], a1[32];
        #pragma unroll
        for (int c = 0; c < 32; ++c) { a0[c] = 0.f; a1[c] = 0.f; }
        #pragma unroll
        for (int ci = 0; ci < 8; ++ci) {
            const float x0 = I[ci*514 + 2*lp + 0];
            const float x1 = I[ci*514 + 2*lp + 1];
            const float x2 = I[ci*514 + 2*lp + 2];
            const float x3 = I[ci*514 + 2*lp + 3];
            #pragma unroll
            for (int co = 0; co < 32; ++co) {
                const float W0 = pw1[(co*8 + ci)*3 + 0];
                const float W1 = pw1[(co*8 + ci)*3 + 1];
                const float W2 = pw1[(co*8 + ci)*3 + 2];
                a0[co] += W0*x0 + W1*x1 + W2*x2;
                a1[co] += W0*x1 + W1*x2 + W2*x3;
            }
        }
        #pragma unroll
        for (int co = 0; co < 32; ++co) {
            float v = fmaxf(a0[co]*sc1[co] + sh1[co], a1[co]*sc1[co] + sh1[co]);
            B1[co*258 + 1 + lp] = fmaxf(v, 0.f);
        }
    }
    __syncthreads();   // I dead after this point; B2 may be written

    // ---- stage 2: conv2 (32 -> 64, L=256) + BN + ReLU + pool2 -> B2 ----
    {
        if (tid < 64) { B2[tid*130] = 0.f; B2[tid*130 + 129] = 0.f; }
        const int lp = tid & 127;                                     // 0..127
        const int cobase = __builtin_amdgcn_readfirstlane(tid >> 7) * 32; // wave-uniform
        float a0[32], a1[32];
        #pragma unroll
        for (int c = 0; c < 32; ++c) { a0[c] = 0.f; a1[c] = 0.f; }
        for (int ci = 0; ci < 32; ++ci) {
            const float x0 = B1[ci*258 + 2*lp + 0];
            const float x1 = B1[ci*258 + 2*lp + 1];
            const float x2 = B1[ci*258 + 2*lp + 2];
            const float x3 = B1[ci*258 + 2*lp + 3];
            #pragma unroll
            for (int j = 0; j < 32; ++j) {
                const int co = cobase + j;
                const float W0 = pw2[(co*32 + ci)*3 + 0];
                const float W1 = pw2[(co*32 + ci)*3 + 1];
                const float W2 = pw2[(co*32 + ci)*3 + 2];
                a0[j] += W0*x0 + W1*x1 + W2*x2;
                a1[j] += W0*x1 + W1*x2 + W2*x3;
            }
        }
        #pragma unroll
        for (int j = 0; j < 32; ++j) {
            const int co = cobase + j;
            float v = fmaxf(a0[j]*sc2[co] + sh2[co], a1[j]*sc2[co] + sh2[co]);
            B2[co*130 + 1 + lp] = fmaxf(v, 0.f);
        }
    }
    __syncthreads();   // B1 dead after this point; B3 may be written

    // ---- stage 3: conv3 (64 -> 128, L=128) + BN + ReLU + pool2 -> B3 ----
    {
        const int lp = tid & 63;                                      // 0..63
        const int cobase = __builtin_amdgcn_readfirstlane(tid >> 6) * 32; // wave-uniform
        float a0[32], a1[32];
        #pragma unroll
        for (int c = 0; c < 32; ++c) { a0[c] = 0.f; a1[c] = 0.f; }
        for (int ci = 0; ci < 64; ++ci) {
            const float x0 = B2[ci*130 + 2*lp + 0];
            const float x1 = B2[ci*130 + 2*lp + 1];
            const float x2 = B2[ci*130 + 2*lp + 2];
            const float x3 = B2[ci*130 + 2*lp + 3];
            #pragma unroll
            for (int j = 0; j < 32; ++j) {
                const int co = cobase + j;
                const float W0 = pw3[(co*64 + ci)*3 + 0];
                const float W1 = pw3[(co*64 + ci)*3 + 1];
                const float W2 = pw3[(co*64 + ci)*3 + 2];
                a0[j] += W0*x0 + W1*x1 + W2*x2;
                a1[j] += W0*x1 + W1*x2 + W2*x3;
            }
        }
        #pragma unroll
        for (int j = 0; j < 32; ++j) {
            const int co = cobase + j;
            float v = fmaxf(a0[j]*sc3[co] + sh3[co], a1[j]*sc3[co] + sh3[co]);
            B3[co*64 + lp] = fmaxf(v, 0.f);
        }
    }
    __syncthreads();

    // ---- stage 4: mean over L=64 -> featm[128] ----
    if (tid < 128) {
        float s = 0.f;
        // rotate start index so 32 consecutive threads hit distinct banks
        for (int i = 0; i < 64; ++i) {
            int lp = (i + tid) & 63;
            s += B3[tid*64 + lp];
        }
        featm[tid] = s * (1.0f / 64.0f);
    }
    __syncthreads();

    // ---- stage 5: linear 128->128 + BN + ReLU ----
    if (tid < 128) {
        const float* wr = pwf + (size_t)tid * 128;
        float s = 0.f;
        #pragma unroll 4
        for (int i = 0; i < 128; i += 4) {
            float4 w4 = *(const float4*)(wr + i);
            s += w4.x*featm[i] + w4.y*featm[i+1] + w4.z*featm[i+2] + w4.w*featm[i+3];
        }
        s += pbf[tid];
        s = (s - pmf[tid]) * (pgf[tid] * rsqrtf(pvf[tid] + EPS_BN)) + pbef[tid];
        featr[tid] = fmaxf(s, 0.f);
    }
    __syncthreads();

    // ---- stage 6: L2 normalize and write out ----
    if (tid < 128) {
        float ss = 0.f;
        for (int i = 0; i < 128; ++i) ss += featr[i] * featr[i];  // broadcast reads
        float n = fmaxf(sqrtf(ss), 1e-12f);
        feat_out[(size_t)sid * 128 + tid] = featr[tid] / n;
    }
}

// ---------------------------------------------------------------------------
// Prototypes: block = (b*NWAY + w), 128 threads (one per feature)
// ---------------------------------------------------------------------------
__global__ __launch_bounds__(128) void proto_kernel(
    const float* __restrict__ feat_s, const int* __restrict__ s_lab,
    float* __restrict__ protos)
{
    const int b = blockIdx.x / NWAY;
    const int w = blockIdx.x % NWAY;
    const int f = threadIdx.x;
    const float* sf = feat_s + (size_t)b * NSHOTB * 128;
    const int* lab = s_lab + b * NSHOTB;
    float acc = 0.f;
    int cnt = 0;
    for (int s = 0; s < NSHOTB; ++s) {
        int lv = lab[s];                 // thread-uniform -> scalar load
        if (lv == w) { acc += sf[s*128 + f]; cnt++; }
    }
    protos[(size_t)blockIdx.x * 128 + f] = acc / (float)cnt;
}

// ---------------------------------------------------------------------------
// Distances: one thread per (b, q, w); out = -sqrt(sum_f (qf-proto)^2)
// ---------------------------------------------------------------------------
__global__ __launch_bounds__(256) void dist_kernel(
    const float* __restrict__ feat_q, const float* __restrict__ protos,
    float* __restrict__ out)
{
    int idx = blockIdx.x * 256 + threadIdx.x;
    if (idx >= 32 * NQB * NWAY) return;
    int b = idx / (NQB * NWAY);
    int r = idx - b * (NQB * NWAY);
    int q = r / NWAY;
    int w = r - q * NWAY;
    const float* qf = feat_q + (size_t)(b * NQB + q) * 128;
    const float* pp = protos + (size_t)(b * NWAY + w) * 128;
    float d2 = 0.f;
    #pragma unroll 4
    for (int i = 0; i < 128; ++i) { float d = qf[i] - pp[i]; d2 += d * d; }
    out[idx] = -sqrtf(fmaxf(d2, 0.f));
}

// ---------------------------------------------------------------------------
extern "C" void kernel_launch(void* const* d_in, const int* in_sizes, int n_in,
                              void* d_out, int out_size, void* d_ws, size_t ws_size,
                              hipStream_t stream) {
    const float* s_img = (const float*)d_in[0];
    const float* q_img = (const float*)d_in[1];
    const int*   s_lab = (const int*)d_in[2];
    const float* pw1  = (const float*)d_in[3];
    const float* pb1  = (const float*)d_in[4];
    const float* pg1  = (const float*)d_in[5];
    const float* pbe1 = (const float*)d_in[6];
    const float* pm1  = (const float*)d_in[7];
    const float* pv1  = (const float*)d_in[8];
    const float* pw2  = (const float*)d_in[9];
    const float* pb2  = (const float*)d_in[10];
    const float* pg2  = (const float*)d_in[11];
    const float* pbe2 = (const float*)d_in[12];
    const float* pm2  = (const float*)d_in[13];
    const float* pv2  = (const float*)d_in[14];
    const float* pw3  = (const float*)d_in[15];
    const float* pb3  = (const float*)d_in[16];
    const float* pg3  = (const float*)d_in[17];
    const float* pbe3 = (const float*)d_in[18];
    const float* pm3  = (const float*)d_in[19];
    const float* pv3  = (const float*)d_in[20];
    const float* pwf  = (const float*)d_in[21];
    const float* pbf  = (const float*)d_in[22];
    const float* pgf  = (const float*)d_in[23];
    const float* pbef = (const float*)d_in[24];
    const float* pmf  = (const float*)d_in[25];
    const float* pvf  = (const float*)d_in[26];

    float* feat   = (float*)d_ws;                 // [9600, 128] fp32
    float* protos = feat + (size_t)NSAMP * 128;   // [32, 20, 128]
    float* out    = (float*)d_out;                // [32, 100, 20]

    encoder_kernel<<<NSAMP, 256, 0, stream>>>(
        s_img, q_img,
        pw1, pb1, pg1, pbe1, pm1, pv1,
        pw2, pb2, pg2, pbe2, pm2, pv2,
        pw3, pb3, pg3, pbe3, pm3, pv3,
        pwf, pbf, pgf, pbef, pmf, pvf,
        feat);

    proto_kernel<<<32 * NWAY, 128, 0, stream>>>(feat, s_lab, protos);

    dist_kernel<<<(32 * NQB * NWAY + 255) / 256, 256, 0, stream>>>(
        feat + (size_t)NSUP * 128, protos, out);
}

// Round 2
// 2014.459 us; speedup vs baseline: 1.7191x; 1.7191x over previous
//
#include <hip/hip_runtime.h>
#include <math.h>

#define EPS_BN 1e-5f

// Problem constants (from reference setup_inputs):
// B=32, NS=200, NQ=100, C=8, L=512, H=32, F=128, N_WAY=20
#define NSUP   6400      // B*NS
#define NQRY   3200      // B*NQ
#define NSAMP  9600
#define NWAY   20
#define NSHOTB 200       // NS per batch
#define NQB    100       // NQ per batch

// ===========================================================================
// SPLIT PATH
// ===========================================================================

// ---------------------------------------------------------------------------
// Kernel 1: conv1 (8->32, L=512) + BN + ReLU + pool2 -> B1 (LDS)
//           conv2 (32->64, L=256) + BN + ReLU + pool2 -> Y2 (global)
// One block per sample, 256 threads. LDS ~50 KB -> 3 blocks/CU.
// ---------------------------------------------------------------------------
__global__ __launch_bounds__(256) void conv12_kernel(
    const float* __restrict__ s_img, const float* __restrict__ q_img,
    const float* __restrict__ pw1, const float* __restrict__ pb1,
    const float* __restrict__ pg1, const float* __restrict__ pbe1,
    const float* __restrict__ pm1, const float* __restrict__ pv1,
    const float* __restrict__ pw2, const float* __restrict__ pb2,
    const float* __restrict__ pg2, const float* __restrict__ pbe2,
    const float* __restrict__ pm2, const float* __restrict__ pv2,
    float* __restrict__ Y2)
{
    __shared__ float I[8 * 514];      // 4112 floats, halo cols
    __shared__ float B1[32 * 258];    // 8256 floats, halo cols
    __shared__ float sc1[32], sh1[32], sc2[64], sh2[64];

    const int tid = threadIdx.x;
    const int sid = blockIdx.x;
    const float* xin = (sid < NSUP) ? (s_img + (size_t)sid * 4096)
                                    : (q_img + (size_t)(sid - NSUP) * 4096);

    // fold BN params
    if (tid < 32) {
        float s = pg1[tid] * rsqrtf(pv1[tid] + EPS_BN);
        sc1[tid] = s; sh1[tid] = (pb1[tid] - pm1[tid]) * s + pbe1[tid];
    } else if (tid < 96) {
        int c = tid - 32;
        float s = pg2[c] * rsqrtf(pv2[c] + EPS_BN);
        sc2[c] = s; sh2[c] = (pb2[c] - pm2[c]) * s + pbe2[c];
    }
    // halos
    if (tid < 32) { B1[tid*258] = 0.f; B1[tid*258 + 257] = 0.f; }
    if (tid < 8)  { I[tid*514] = 0.f;  I[tid*514 + 513] = 0.f; }
    // stage input
    #pragma unroll
    for (int k = 0; k < 4; ++k) {
        int p = k*256 + tid;                 // float4 index, 1024 total
        float4 v = ((const float4*)xin)[p];
        int fi = p * 4;
        int ci = fi >> 9;
        int l  = fi & 511;
        float* dst = &I[ci*514 + 1 + l];
        dst[0] = v.x; dst[1] = v.y; dst[2] = v.z; dst[3] = v.w;
    }
    __syncthreads();

    // ---- conv1: lp = tid (0..255 pooled position) ----
    {
        const int lp = tid;
        float a0[32], a1[32];
        #pragma unroll
        for (int c = 0; c < 32; ++c) { a0[c] = 0.f; a1[c] = 0.f; }
        #pragma unroll
        for (int ci = 0; ci < 8; ++ci) {
            const float x0 = I[ci*514 + 2*lp + 0];
            const float x1 = I[ci*514 + 2*lp + 1];
            const float x2 = I[ci*514 + 2*lp + 2];
            const float x3 = I[ci*514 + 2*lp + 3];
            #pragma unroll
            for (int co = 0; co < 32; ++co) {
                const float W0 = pw1[(co*8 + ci)*3 + 0];
                const float W1 = pw1[(co*8 + ci)*3 + 1];
                const float W2 = pw1[(co*8 + ci)*3 + 2];
                a0[co] += W0*x0 + W1*x1 + W2*x2;
                a1[co] += W0*x1 + W1*x2 + W2*x3;
            }
        }
        #pragma unroll
        for (int co = 0; co < 32; ++co) {
            float v = fmaxf(a0[co]*sc1[co] + sh1[co], a1[co]*sc1[co] + sh1[co]);
            B1[co*258 + 1 + lp] = fmaxf(v, 0.f);
        }
    }
    __syncthreads();

    // ---- conv2: lp = tid&127, co-group = tid>>7 (wave-uniform) ----
    {
        const int lp = tid & 127;
        const int cobase = __builtin_amdgcn_readfirstlane(tid >> 7) * 32;
        float a0[32], a1[32];
        #pragma unroll
        for (int c = 0; c < 32; ++c) { a0[c] = 0.f; a1[c] = 0.f; }
        for (int ci = 0; ci < 32; ++ci) {
            const float x0 = B1[ci*258 + 2*lp + 0];
            const float x1 = B1[ci*258 + 2*lp + 1];
            const float x2 = B1[ci*258 + 2*lp + 2];
            const float x3 = B1[ci*258 + 2*lp + 3];
            #pragma unroll
            for (int j = 0; j < 32; ++j) {
                const int co = cobase + j;
                const float W0 = pw2[(co*32 + ci)*3 + 0];
                const float W1 = pw2[(co*32 + ci)*3 + 1];
                const float W2 = pw2[(co*32 + ci)*3 + 2];
                a0[j] += W0*x0 + W1*x1 + W2*x2;
                a1[j] += W0*x1 + W1*x2 + W2*x3;
            }
        }
        float* ybase = Y2 + (size_t)sid * 8192;
        #pragma unroll
        for (int j = 0; j < 32; ++j) {
            const int co = cobase + j;
            float v = fmaxf(a0[j]*sc2[co] + sh2[co], a1[j]*sc2[co] + sh2[co]);
            ybase[co*128 + lp] = fmaxf(v, 0.f);
        }
    }
}

// ---------------------------------------------------------------------------
// Kernel 2: conv3 (64->128, L=128) + BN + ReLU + pool2 -> B3 (LDS, aliases Y2
// stage) -> mean -> linear -> BN -> ReLU -> L2 normalize -> feat (global)
// One block per sample, 256 threads. LDS ~35 KB -> 4 blocks/CU (LDS-wise).
// ---------------------------------------------------------------------------
__global__ __launch_bounds__(256) void conv3tail_kernel(
    const float* __restrict__ Y2,
    const float* __restrict__ pw3, const float* __restrict__ pb3,
    const float* __restrict__ pg3, const float* __restrict__ pbe3,
    const float* __restrict__ pm3, const float* __restrict__ pv3,
    const float* __restrict__ pwf, const float* __restrict__ pbf,
    const float* __restrict__ pgf, const float* __restrict__ pbef,
    const float* __restrict__ pmf, const float* __restrict__ pvf,
    float* __restrict__ feat_out)
{
    __shared__ float S[64 * 130];     // 8320 floats: staged Y2 w/ halos; later B3 (128x64=8192)
    __shared__ float sc3[128], sh3[128];
    __shared__ float featm[128], featr[128];

    const int tid = threadIdx.x;
    const int sid = blockIdx.x;

    if (tid < 128) {
        float s = pg3[tid] * rsqrtf(pv3[tid] + EPS_BN);
        sc3[tid] = s; sh3[tid] = (pb3[tid] - pm3[tid]) * s + pbe3[tid];
    }
    if (tid < 64) { S[tid*130] = 0.f; S[tid*130 + 129] = 0.f; }
    const float* ybase = Y2 + (size_t)sid * 8192;
    #pragma unroll
    for (int k = 0; k < 8; ++k) {
        int p = k*256 + tid;                 // float4 index, 2048 total
        float4 v = ((const float4*)ybase)[p];
        int fi = p * 4;
        int ci = fi >> 7;
        int l  = fi & 127;
        float* dst = &S[ci*130 + 1 + l];
        dst[0] = v.x; dst[1] = v.y; dst[2] = v.z; dst[3] = v.w;
    }
    __syncthreads();

    // ---- conv3: lp = tid&63, co-group = tid>>6 (wave-uniform) ----
    float pooled[32];
    const int lp = tid & 63;
    const int cobase = __builtin_amdgcn_readfirstlane(tid >> 6) * 32;
    {
        float a0[32], a1[32];
        #pragma unroll
        for (int c = 0; c < 32; ++c) { a0[c] = 0.f; a1[c] = 0.f; }
        for (int ci = 0; ci < 64; ++ci) {
            const float x0 = S[ci*130 + 2*lp + 0];
            const float x1 = S[ci*130 + 2*lp + 1];
            const float x2 = S[ci*130 + 2*lp + 2];
            const float x3 = S[ci*130 + 2*lp + 3];
            #pragma unroll
            for (int j = 0; j < 32; ++j) {
                const int co = cobase + j;
                const float W0 = pw3[(co*64 + ci)*3 + 0];
                const float W1 = pw3[(co*64 + ci)*3 + 1];
                const float W2 = pw3[(co*64 + ci)*3 + 2];
                a0[j] += W0*x0 + W1*x1 + W2*x2;
                a1[j] += W0*x1 + W1*x2 + W2*x3;
            }
        }
        #pragma unroll
        for (int j = 0; j < 32; ++j) {
            const int co = cobase + j;
            float v = fmaxf(a0[j]*sc3[co] + sh3[co], a1[j]*sc3[co] + sh3[co]);
            pooled[j] = fmaxf(v, 0.f);
        }
    }
    __syncthreads();   // all reads of staged Y2 done; safe to overwrite with B3
    #pragma unroll
    for (int j = 0; j < 32; ++j) S[(cobase + j)*64 + lp] = pooled[j];
    __syncthreads();

    // ---- mean over L=64 ----
    if (tid < 128) {
        float s = 0.f;
        for (int i = 0; i < 64; ++i) {
            int l = (i + tid) & 63;          // rotate to spread banks
            s += S[tid*64 + l];
        }
        featm[tid] = s * (1.0f / 64.0f);
    }
    __syncthreads();

    // ---- linear 128->128 + BN + ReLU ----
    if (tid < 128) {
        const float* wr = pwf + (size_t)tid * 128;
        float s = 0.f;
        #pragma unroll 4
        for (int i = 0; i < 128; i += 4) {
            float4 w4 = *(const float4*)(wr + i);
            s += w4.x*featm[i] + w4.y*featm[i+1] + w4.z*featm[i+2] + w4.w*featm[i+3];
        }
        s += pbf[tid];
        s = (s - pmf[tid]) * (pgf[tid] * rsqrtf(pvf[tid] + EPS_BN)) + pbef[tid];
        featr[tid] = fmaxf(s, 0.f);
    }
    __syncthreads();

    // ---- L2 normalize ----
    if (tid < 128) {
        float ss = 0.f;
        for (int i = 0; i < 128; ++i) ss += featr[i] * featr[i];  // broadcast reads
        float n = fmaxf(sqrtf(ss), 1e-12f);
        feat_out[(size_t)sid * 128 + tid] = featr[tid] / n;
    }
}

// ===========================================================================
// MONOLITHIC FALLBACK (round-1 kernel) — used when ws_size is too small for
// the 315 MB Y2 intermediate. Deterministic branch on ws_size (graph-safe).
// ===========================================================================
__global__ __launch_bounds__(256) void encoder_mono(
    const float* __restrict__ s_img, const float* __restrict__ q_img,
    const float* __restrict__ pw1, const float* __restrict__ pb1,
    const float* __restrict__ pg1, const float* __restrict__ pbe1,
    const float* __restrict__ pm1, const float* __restrict__ pv1,
    const float* __restrict__ pw2, const float* __restrict__ pb2,
    const float* __restrict__ pg2, const float* __restrict__ pbe2,
    const float* __restrict__ pm2, const float* __restrict__ pv2,
    const float* __restrict__ pw3, const float* __restrict__ pb3,
    const float* __restrict__ pg3, const float* __restrict__ pbe3,
    const float* __restrict__ pm3, const float* __restrict__ pv3,
    const float* __restrict__ pwf, const float* __restrict__ pbf,
    const float* __restrict__ pgf, const float* __restrict__ pbef,
    const float* __restrict__ pmf, const float* __restrict__ pvf,
    float* __restrict__ feat_out)
{
    __shared__ float smem[16576];
    __shared__ float sc1[32], sh1[32], sc2[64], sh2[64], sc3[128], sh3[128];
    __shared__ float featm[128], featr[128];

    float* const I  = smem;
    float* const B2 = smem;
    float* const B1 = smem + 8320;
    float* const B3 = smem + 8320;

    const int tid = threadIdx.x;
    const int sid = blockIdx.x;
    const float* xin = (sid < NSUP) ? (s_img + (size_t)sid * 4096)
                                    : (q_img + (size_t)(sid - NSUP) * 4096);

    if (tid < 32) {
        float s = pg1[tid] * rsqrtf(pv1[tid] + EPS_BN);
        sc1[tid] = s; sh1[tid] = (pb1[tid] - pm1[tid]) * s + pbe1[tid];
    } else if (tid < 96) {
        int c = tid - 32;
        float s = pg2[c] * rsqrtf(pv2[c] + EPS_BN);
        sc2[c] = s; sh2[c] = (pb2[c] - pm2[c]) * s + pbe2[c];
    } else if (tid < 224) {
        int c = tid - 96;
        float s = pg3[c] * rsqrtf(pv3[c] + EPS_BN);
        sc3[c] = s; sh3[c] = (pb3[c] - pm3[c]) * s + pbe3[c];
    }
    if (tid < 32) { B1[tid*258] = 0.f; B1[tid*258 + 257] = 0.f; }
    #pragma unroll
    for (int k = 0; k < 4; ++k) {
        int p = k*256 + tid;
        float4 v = ((const float4*)xin)[p];
        int fi = p * 4;
        int ci = fi >> 9;
        int l  = fi & 511;
        float* dst = &I[ci*514 + 1 + l];
        dst[0] = v.x; dst[1] = v.y; dst[2] = v.z; dst[3] = v.w;
    }
    if (tid < 8) { I[tid*514] = 0.f; I[tid*514 + 513] = 0.f; }
    __syncthreads();

    {
        const int lp = tid;
        float a0[32], a1[32];
        #pragma unroll
        for (int c = 0; c < 32; ++c) { a0[c] = 0.f; a1[c] = 0.f; }
        #pragma unroll
        for (int ci = 0; ci < 8; ++ci) {
            const float x0 = I[ci*514 + 2*lp + 0];
            const float x1 = I[ci*514 + 2*lp + 1];
            const float x2 = I[ci*514 + 2*lp + 2];
            const float x3 = I[ci*514 + 2*lp + 3];
            #pragma unroll
            for (int co = 0; co < 32; ++co) {
                const float W0 = pw1[(co*8 + ci)*3 + 0];
                const float W1 = pw1[(co*8 + ci)*3 + 1];
                const float W2 = pw1[(co*8 + ci)*3 + 2];
                a0[co] += W0*x0 + W1*x1 + W2*x2;
                a1[co] += W0*x1 + W1*x2 + W2*x3;
            }
        }
        #pragma unroll
        for (int co = 0; co < 32; ++co) {
            float v = fmaxf(a0[co]*sc1[co] + sh1[co], a1[co]*sc1[co] + sh1[co]);
            B1[co*258 + 1 + lp] = fmaxf(v, 0.f);
        }
    }
    __syncthreads();

    {
        if (tid < 64) { B2[tid*130] = 0.f; B2[tid*130 + 129] = 0.f; }
        const int lp = tid & 127;
        const int cobase = __builtin_amdgcn_readfirstlane(tid >> 7) * 32;
        float a0[32], a1[32];
        #pragma unroll
        for (int c = 0; c < 32; ++c) { a0[c] = 0.f; a1[c] = 0.f; }
        for (int ci = 0; ci < 32; ++ci) {
            const float x0 = B1[ci*258 + 2*lp + 0];
            const float x1 = B1[ci*258 + 2*lp + 1];
            const float x2 = B1[ci*258 + 2*lp + 2];
            const float x3 = B1[ci*258 + 2*lp + 3];
            #pragma unroll
            for (int j = 0; j < 32; ++j) {
                const int co = cobase + j;
                const float W0 = pw2[(co*32 + ci)*3 + 0];
                const float W1 = pw2[(co*32 + ci)*3 + 1];
                const float W2 = pw2[(co*32 + ci)*3 + 2];
                a0[j] += W0*x0 + W1*x1 + W2*x2;
                a1[j] += W0*x1 + W1*x2 + W2*x3;
            }
        }
        #pragma unroll
        for (int j = 0; j < 32; ++j) {
            const int co = cobase + j;
            float v = fmaxf(a0[j]*sc2[co] + sh2[co], a1[j]*sc2[co] + sh2[co]);
            B2[co*130 + 1 + lp] = fmaxf(v, 0.f);
        }
    }
    __syncthreads();

    {
        const int lp = tid & 63;
        const int cobase = __builtin_amdgcn_readfirstlane(tid >> 6) * 32;
        float a0[32], a1[32];
        #pragma unroll
        for (int c = 0; c < 32; ++c) { a0[c] = 0.f; a1[c] = 0.f; }
        for (int ci = 0; ci < 64; ++ci) {
            const float x0 = B2[ci*130 + 2*lp + 0];
            const float x1 = B2[ci*130 + 2*lp + 1];
            const float x2 = B2[ci*130 + 2*lp + 2];
            const float x3 = B2[ci*130 + 2*lp + 3];
            #pragma unroll
            for (int j = 0; j < 32; ++j) {
                const int co = cobase + j;
                const float W0 = pw3[(co*64 + ci)*3 + 0];
                const float W1 = pw3[(co*64 + ci)*3 + 1];
                const float W2 = pw3[(co*64 + ci)*3 + 2];
                a0[j] += W0*x0 + W1*x1 + W2*x2;
                a1[j] += W0*x1 + W1*x2 + W2*x3;
            }
        }
        #pragma unroll
        for (int j = 0; j < 32; ++j) {
            const int co = cobase + j;
            float v = fmaxf(a0[j]*sc3[co] + sh3[co], a1[j]*sc3[co] + sh3[co]);
            B3[co*64 + lp] = fmaxf(v, 0.f);
        }
    }
    __syncthreads();

    if (tid < 128) {
        float s = 0.f;
        for (int i = 0; i < 64; ++i) {
            int lp = (i + tid) & 63;
            s += B3[tid*64 + lp];
        }
        featm[tid] = s * (1.0f / 64.0f);
    }
    __syncthreads();

    if (tid < 128) {
        const float* wr = pwf + (size_t)tid * 128;
        float s = 0.f;
        #pragma unroll 4
        for (int i = 0; i < 128; i += 4) {
            float4 w4 = *(const float4*)(wr + i);
            s += w4.x*featm[i] + w4.y*featm[i+1] + w4.z*featm[i+2] + w4.w*featm[i+3];
        }
        s += pbf[tid];
        s = (s - pmf[tid]) * (pgf[tid] * rsqrtf(pvf[tid] + EPS_BN)) + pbef[tid];
        featr[tid] = fmaxf(s, 0.f);
    }
    __syncthreads();

    if (tid < 128) {
        float ss = 0.f;
        for (int i = 0; i < 128; ++i) ss += featr[i] * featr[i];
        float n = fmaxf(sqrtf(ss), 1e-12f);
        feat_out[(size_t)sid * 128 + tid] = featr[tid] / n;
    }
}

// ---------------------------------------------------------------------------
// Prototypes: block = (b*NWAY + w), 128 threads (one per feature)
// ---------------------------------------------------------------------------
__global__ __launch_bounds__(128) void proto_kernel(
    const float* __restrict__ feat_s, const int* __restrict__ s_lab,
    float* __restrict__ protos)
{
    const int b = blockIdx.x / NWAY;
    const int w = blockIdx.x % NWAY;
    const int f = threadIdx.x;
    const float* sf = feat_s + (size_t)b * NSHOTB * 128;
    const int* lab = s_lab + b * NSHOTB;
    float acc = 0.f;
    int cnt = 0;
    for (int s = 0; s < NSHOTB; ++s) {
        int lv = lab[s];
        if (lv == w) { acc += sf[s*128 + f]; cnt++; }
    }
    protos[(size_t)blockIdx.x * 128 + f] = acc / (float)cnt;
}

// ---------------------------------------------------------------------------
// Distances: one thread per (b, q, w); out = -sqrt(sum_f (qf-proto)^2)
// ---------------------------------------------------------------------------
__global__ __launch_bounds__(256) void dist_kernel(
    const float* __restrict__ feat_q, const float* __restrict__ protos,
    float* __restrict__ out)
{
    int idx = blockIdx.x * 256 + threadIdx.x;
    if (idx >= 32 * NQB * NWAY) return;
    int b = idx / (NQB * NWAY);
    int r = idx - b * (NQB * NWAY);
    int q = r / NWAY;
    int w = r - q * NWAY;
    const float* qf = feat_q + (size_t)(b * NQB + q) * 128;
    const float* pp = protos + (size_t)(b * NWAY + w) * 128;
    float d2 = 0.f;
    #pragma unroll 4
    for (int i = 0; i < 128; ++i) { float d = qf[i] - pp[i]; d2 += d * d; }
    out[idx] = -sqrtf(fmaxf(d2, 0.f));
}

// ---------------------------------------------------------------------------
extern "C" void kernel_launch(void* const* d_in, const int* in_sizes, int n_in,
                              void* d_out, int out_size, void* d_ws, size_t ws_size,
                              hipStream_t stream) {
    const float* s_img = (const float*)d_in[0];
    const float* q_img = (const float*)d_in[1];
    const int*   s_lab = (const int*)d_in[2];
    const float* pw1  = (const float*)d_in[3];
    const float* pb1  = (const float*)d_in[4];
    const float* pg1  = (const float*)d_in[5];
    const float* pbe1 = (const float*)d_in[6];
    const float* pm1  = (const float*)d_in[7];
    const float* pv1  = (const float*)d_in[8];
    const float* pw2  = (const float*)d_in[9];
    const float* pb2  = (const float*)d_in[10];
    const float* pg2  = (const float*)d_in[11];
    const float* pbe2 = (const float*)d_in[12];
    const float* pm2  = (const float*)d_in[13];
    const float* pv2  = (const float*)d_in[14];
    const float* pw3  = (const float*)d_in[15];
    const float* pb3  = (const float*)d_in[16];
    const float* pg3  = (const float*)d_in[17];
    const float* pbe3 = (const float*)d_in[18];
    const float* pm3  = (const float*)d_in[19];
    const float* pv3  = (const float*)d_in[20];
    const float* pwf  = (const float*)d_in[21];
    const float* pbf  = (const float*)d_in[22];
    const float* pgf  = (const float*)d_in[23];
    const float* pbef = (const float*)d_in[24];
    const float* pmf  = (const float*)d_in[25];
    const float* pvf  = (const float*)d_in[26];

    const size_t y2_elems   = (size_t)NSAMP * 8192;              // 78.6M floats
    const size_t feat_elems = (size_t)NSAMP * 128;
    const size_t prot_elems = (size_t)32 * NWAY * 128;
    const size_t need_split = (y2_elems + feat_elems + prot_elems) * sizeof(float);

    float* out = (float*)d_out;

    if (ws_size >= need_split) {
        float* Y2     = (float*)d_ws;
        float* feat   = Y2 + y2_elems;
        float* protos = feat + feat_elems;

        conv12_kernel<<<NSAMP, 256, 0, stream>>>(
            s_img, q_img,
            pw1, pb1, pg1, pbe1, pm1, pv1,
            pw2, pb2, pg2, pbe2, pm2, pv2,
            Y2);
        conv3tail_kernel<<<NSAMP, 256, 0, stream>>>(
            Y2,
            pw3, pb3, pg3, pbe3, pm3, pv3,
            pwf, pbf, pgf, pbef, pmf, pvf,
            feat);
        proto_kernel<<<32 * NWAY, 128, 0, stream>>>(feat, s_lab, protos);
        dist_kernel<<<(32 * NQB * NWAY + 255) / 256, 256, 0, stream>>>(
            feat + (size_t)NSUP * 128, protos, out);
    } else {
        float* feat   = (float*)d_ws;
        float* protos = feat + feat_elems;

        encoder_mono<<<NSAMP, 256, 0, stream>>>(
            s_img, q_img,
            pw1, pb1, pg1, pbe1, pm1, pv1,
            pw2, pb2, pg2, pbe2, pm2, pv2,
            pw3, pb3, pg3, pbe3, pm3, pv3,
            pwf, pbf, pgf, pbef, pmf, pvf,
            feat);
        proto_kernel<<<32 * NWAY, 128, 0, stream>>>(feat, s_lab, protos);
        dist_kernel<<<(32 * NQB * NWAY + 255) / 256, 256, 0, stream>>>(
            feat + (size_t)NSUP * 128, protos, out);
    }
}